// Round 10
// baseline (349.634 us; speedup 1.0000x reference)
//
#include <hip/hip_runtime.h>

// SpatialEncoding: out[src,dst] = b[min(path_len,5)-1], last-write-wins in p order.
//
// R10: TWO kernels (R9 had four). K1 sorts each 12288-pair tile by bucket in
// LDS and writes the sorted u32 records to the block's OWN ws region plus a
// per-block run-start table. K2 (one block per bucket) gathers bucket c's runs
// directly from all 652 block regions (one thread per run), merges with LDS
// atomicMax, decodes, stores. This deletes R9's flush pass (32MB W + 32MB R +
// 88M-LDS-read binary search), the scan-over-blocks kernel, and the second
// read of the index arrays. Zero global atomics (R1/R2/R6 lesson), zero
// memsets, no NT stores (R5 lesson).
//
//   rec(u32) = off(14 [31:18]) | (local_p+1)(15 [17:3]) | clamped(3 [2:0])
//   merge key = ((blk+1)<<18) | (rec & 0x3FFFF)   -- 28 bits, monotone in
//   global pair order (blk, lp); 0 == empty cell. numpy last-write-wins ✓
//   starts[blk]: u16[2200] (buckets 2198/2199 count 0 => entry 2198 == total).
//   NPACK=1100 keeps all packed-u16 owner accesses in-bounds (R7 lesson).

#define BSHIFT 14
#define BCELLS (1 << BSHIFT)            // 16384 cells per bucket
#define NBUCK  2198                     // ceil(36e6 / 16384)
#define NPACK  1100                     // 2200 u16 (pad pair keeps owners in-bounds)
#define NOWN   550                      // owner threads, 4 buckets each
#define THREADS 1024
#define TILE   12288                    // pairs per sort block
#define ROWW   1104                     // starts row stride in u32 (2208 u16)

// ---------------- K1: tile bucket-sort -> block-local sorted records ----------------
__global__ __launch_bounds__(THREADS) void se_sort(
        const int* __restrict__ src_idx,
        const int* __restrict__ dst_idx,
        const int* __restrict__ path_len,
        unsigned int* __restrict__ recsW,        // ws: [nblk][TILE] u32
        unsigned int* __restrict__ startsW,      // ws: [nblk][ROWW] u32 (u16 pairs)
        int P, int n) {
    __shared__ unsigned int histP[NPACK];        // run starts (packed u16)
    __shared__ unsigned int curP[NPACK];         // counts -> cursors
    __shared__ unsigned int stage[TILE];         // 48 KB sorted staging
    __shared__ unsigned int scr[34];

    int t = threadIdx.x;
    int start = blockIdx.x * TILE;

    for (int i = t; i < NPACK; i += THREADS) curP[i] = 0u;
    __syncthreads();

    // Phase A: read 12 pairs/thread (int4 x3, coalesced), keep in registers
    int cells[12];
    unsigned int lows[12];
#pragma unroll
    for (int j = 0; j < 3; ++j) {
        int base = start + j * (THREADS * 4) + t * 4;
        int k0 = j * 4;
        if (base + 3 < P) {
            int4 s = *reinterpret_cast<const int4*>(src_idx + base);
            int4 d = *reinterpret_cast<const int4*>(dst_idx + base);
            int4 l = *reinterpret_cast<const int4*>(path_len + base);
            int lp = base - start;
            cells[k0]     = s.x * n + d.x;
            cells[k0 + 1] = s.y * n + d.y;
            cells[k0 + 2] = s.z * n + d.z;
            cells[k0 + 3] = s.w * n + d.w;
            lows[k0]     = ((unsigned int)(lp + 1) << 3) | (unsigned int)((l.x < 5 ? l.x : 5) - 1);
            lows[k0 + 1] = ((unsigned int)(lp + 2) << 3) | (unsigned int)((l.y < 5 ? l.y : 5) - 1);
            lows[k0 + 2] = ((unsigned int)(lp + 3) << 3) | (unsigned int)((l.z < 5 ? l.z : 5) - 1);
            lows[k0 + 3] = ((unsigned int)(lp + 4) << 3) | (unsigned int)((l.w < 5 ? l.w : 5) - 1);
        } else {
#pragma unroll
            for (int jj = 0; jj < 4; ++jj) {
                int p = base + jj;
                if (p < P) {
                    cells[k0 + jj] = src_idx[p] * n + dst_idx[p];
                    int len = path_len[p];
                    int cl = (len < 5 ? len : 5) - 1;
                    lows[k0 + jj] = ((unsigned int)(p - start + 1) << 3) | (unsigned int)cl;
                } else {
                    cells[k0 + jj] = -1;
                    lows[k0 + jj] = 0u;
                }
            }
        }
    }
    // histogram buckets (packed u16 LDS counters)
#pragma unroll
    for (int k = 0; k < 12; ++k) {
        if (cells[k] >= 0) {
            unsigned int c = (unsigned int)cells[k] >> BSHIFT;
            atomicAdd(&curP[c >> 1], (c & 1) ? 0x10000u : 1u);
        }
    }
    __syncthreads();

    // Phase B: block-wide exclusive scan of counts -> run starts (histP).
    // Buckets 2198/2199 have count 0, so entry 2198 lands on total (sentinel).
    unsigned int l0 = 0, l1 = 0, l2v = 0, l3 = 0, s = 0;
    if (t < NOWN) {
        unsigned int w0 = curP[2 * t], w1 = curP[2 * t + 1];
        unsigned int v0 = w0 & 0xFFFFu, v1 = w0 >> 16;
        unsigned int v2 = w1 & 0xFFFFu, v3 = w1 >> 16;
        l0 = 0; l1 = v0; l2v = v0 + v1; l3 = v0 + v1 + v2;
        s = v0 + v1 + v2 + v3;
    }
    unsigned int x = s;
    for (int d = 1; d < 64; d <<= 1) {
        unsigned int y = (unsigned int)__shfl_up((int)x, d, 64);
        if ((t & 63) >= d) x += y;
    }
    if ((t & 63) == 63) scr[t >> 6] = x;
    __syncthreads();
    if (t == 0) {
        unsigned int acc = 0;
        for (int w = 0; w < 16; ++w) { unsigned int v = scr[w]; scr[16 + w] = acc; acc += v; }
        scr[32] = acc;
    }
    __syncthreads();
    unsigned int exc = x - s + scr[16 + (t >> 6)];
    if (t < NOWN) {
        unsigned int st0 = exc + l0, st1 = exc + l1, st2 = exc + l2v, st3 = exc + l3;
        histP[2 * t]     = (st0 & 0xFFFFu) | (st1 << 16);
        histP[2 * t + 1] = (st2 & 0xFFFFu) | (st3 << 16);
    }
    __syncthreads();

    // Phase C: cursors := starts
    for (int i = t; i < NPACK; i += THREADS) curP[i] = histP[i];
    __syncthreads();

    // Phase D: place records into LDS staging, grouped by bucket
#pragma unroll
    for (int k = 0; k < 12; ++k) {
        if (cells[k] >= 0) {
            unsigned int cell = (unsigned int)cells[k];
            unsigned int c = cell >> BSHIFT;
            unsigned int old = atomicAdd(&curP[c >> 1], (c & 1) ? 0x10000u : 1u);
            unsigned int pos = (old >> ((c & 1) * 16)) & 0xFFFFu;
            stage[pos] = ((cell & (BCELLS - 1)) << 18) | lows[k];
        }
    }
    __syncthreads();

    // Phase E: contiguous vectorized dump of sorted records + starts table.
    unsigned int tot = scr[32];
    uint4* dst4 = reinterpret_cast<uint4*>(recsW + (size_t)blockIdx.x * TILE);
    const uint4* st4 = reinterpret_cast<const uint4*>(stage);
    unsigned int n4 = (tot + 3) >> 2;
    for (unsigned int i = t; i < n4; i += THREADS) dst4[i] = st4[i];
    unsigned int* srow = startsW + (size_t)blockIdx.x * ROWW;
    for (int i = t; i < NPACK; i += THREADS) srow[i] = histP[i];
}

// ---------------- K2: per-bucket gather-merge + decode ----------------
__device__ __forceinline__ float se_decode(unsigned int k,
                                           float b0, float b1, float b2,
                                           float b3, float b4) {
    unsigned c = k & 7u;
    float t = (c == 0u) ? b0 : (c == 1u) ? b1 : (c == 2u) ? b2 : (c == 3u) ? b3 : b4;
    return k ? t : 0.0f;
}

__global__ __launch_bounds__(THREADS) void se_merge(
        const unsigned int* __restrict__ recsW,
        const unsigned int* __restrict__ startsW,
        const float* __restrict__ b,
        float* __restrict__ out,
        long long totalCells, int nblk) {
    __shared__ unsigned int tab[BCELLS];      // 64 KB

    int c = blockIdx.x;
    long long baseCell = (long long)c << BSHIFT;
    long long rem = totalCells - baseCell;
    int valid = rem < BCELLS ? (int)rem : BCELLS;

    uint4* tab4 = reinterpret_cast<uint4*>(tab);
    for (int i = threadIdx.x; i < BCELLS / 4; i += THREADS)
        tab4[i] = make_uint4(0u, 0u, 0u, 0u);
    __syncthreads();

    // one thread per block-region: gather bucket c's run, LDS atomicMax merge
    int tr = threadIdx.x;
    if (tr < nblk) {
        const unsigned short* row16 =
            reinterpret_cast<const unsigned short*>(startsW + (size_t)tr * ROWW);
        unsigned int rb0 = row16[c], rb1 = row16[c + 1];
        const unsigned int* rr = recsW + (size_t)tr * TILE;
        unsigned int keyhi = (unsigned int)(tr + 1) << 18;
        for (unsigned int i = rb0; i < rb1; ++i) {
            unsigned int rec = rr[i];
            atomicMax(&tab[rec >> 18], keyhi | (rec & 0x3FFFFu));
        }
    }
    __syncthreads();

    float b0 = b[0], b1 = b[1], b2 = b[2], b3 = b[3], b4 = b[4];
    float* o = out + baseCell;
    int n4 = valid >> 2;
    float4* o4 = reinterpret_cast<float4*>(o);
    for (int i = threadIdx.x; i < n4; i += THREADS) {
        uint4 k = tab4[i];
        float4 v;
        v.x = se_decode(k.x, b0, b1, b2, b3, b4);
        v.y = se_decode(k.y, b0, b1, b2, b3, b4);
        v.z = se_decode(k.z, b0, b1, b2, b3, b4);
        v.w = se_decode(k.w, b0, b1, b2, b3, b4);
        o4[i] = v;
    }
    for (int i = (n4 << 2) + threadIdx.x; i < valid; i += THREADS)
        o[i] = se_decode(tab[i], b0, b1, b2, b3, b4);
}

extern "C" void kernel_launch(void* const* d_in, const int* in_sizes, int n_in,
                              void* d_out, int out_size, void* d_ws, size_t ws_size,
                              hipStream_t stream) {
    // inputs: 0=x [N*128 f32], 1=b [5 f32], 2=src_idx [P i32], 3=dst_idx [P i32], 4=path_len [P i32]
    const float* b        = (const float*)d_in[1];
    const int*   src_idx  = (const int*)d_in[2];
    const int*   dst_idx  = (const int*)d_in[3];
    const int*   path_len = (const int*)d_in[4];
    int P = in_sizes[2];
    int n = in_sizes[0] / 128;                      // N = 6000
    long long totalCells = (long long)n * n;        // 36,000,000
    int nblk = (P + TILE - 1) / TILE;               // 652

    // ws layout: recsW [nblk*TILE u32] (32 MB) then startsW [nblk*ROWW u32]
    // (2.88 MB). Both fully overwritten every call — no memset needed.
    unsigned int* recsW   = (unsigned int*)d_ws;
    unsigned int* startsW = recsW + (size_t)nblk * TILE;

    // K1: per-tile LDS bucket-sort -> block-local sorted records + starts
    se_sort<<<nblk, THREADS, 0, stream>>>(src_idx, dst_idx, path_len,
                                          recsW, startsW, P, n);

    // K2: per-bucket gather-merge from all block regions + decode + store
    se_merge<<<NBUCK, THREADS, 0, stream>>>(recsW, startsW, b, (float*)d_out,
                                            totalCells, nblk);
}

// Round 11
// 326.476 us; speedup vs baseline: 1.0709x; 1.0709x over previous
//
#include <hip/hip_runtime.h>

// SpatialEncoding: out[src,dst] = b[min(path_len,5)-1], last-write-wins in p order.
//
// R11: 4 stages, every fragment proven in a prior passing round.
//  K1 se_sort  (=R10 K1 + counts dump): tile bucket-sort in LDS -> block-local
//              sorted recs (32MB, coalesced) + counts row + starts row.
//  K2 se_scan  (=R9 verbatim): per-bucket exclusive scan over blocks ->
//              bases in countsW (block-major) + transposed basesT (+sentinel).
//  K3 se_repack (new): read own recs coalesced, binary-search bucket over LDS
//              starts (R9-proven search), write rec to its bucket's region in
//              d_out at exact global position. Scattered ~22B runs (write amp
//              ~3x of 32MB — the R6-measured cost, cheaper than R10's 272MB
//              read amp in merge).
//  K4 se_merge (=R9 verbatim): bucket-contiguous gather (one thread per run,
//              contiguous region), LDS atomicMax, decode, coalesced store.
//
//  rec(u32) = off(14 [31:18]) | (local_p+1)(15 [17:3]) | clamped(3 [2:0])
//  merge key = ((blk_rank+1)<<18) | (rec & 0x3FFFF)  -- monotone in global
//  pair order (blk, lp); 0 == empty. numpy last-write-wins ✓
//  Bucket c's records: d_out u32 slots [c*16384, +total_c); totals ~3641+-60
//  (u16 ok); last bucket ~967 vs 4352 valid cells. NPACK=1100 keeps all
//  packed-u16 owner accesses in-bounds (R7 lesson). Zero global atomics.

#define BSHIFT 14
#define BCELLS (1 << BSHIFT)            // 16384 cells per bucket
#define NBUCK  2198                     // ceil(36e6 / 16384)
#define NPACK  1100                     // 2200 u16 (pad pair keeps owners in-bounds)
#define NOWN   550                      // owner threads, 4 buckets each
#define THREADS 1024
#define TILE   12288                    // pairs per sort block
#define SCAN_TB 16                      // buckets per scan block
#define MAXBLK 656                      // >= nblk=652

__device__ __forceinline__ unsigned int unpack16(const unsigned int* A, unsigned int c) {
    return (A[c >> 1] >> ((c & 1) * 16)) & 0xFFFFu;
}

// ---------------- K1: tile bucket-sort -> block-local sorted records ----------------
__global__ __launch_bounds__(THREADS) void se_sort(
        const int* __restrict__ src_idx,
        const int* __restrict__ dst_idx,
        const int* __restrict__ path_len,
        unsigned int* __restrict__ recsW,        // ws: [nblk][TILE] u32
        unsigned int* __restrict__ startsW,      // ws: [nblk][NPACK] u32 (u16 pairs)
        unsigned int* __restrict__ countsW,      // ws: [nblk][NPACK] u32 (u16 pairs)
        int P, int n) {
    __shared__ unsigned int histP[NPACK];        // run starts (packed u16)
    __shared__ unsigned int curP[NPACK];         // counts -> cursors
    __shared__ unsigned int stage[TILE];         // 48 KB sorted staging
    __shared__ unsigned int scr[34];

    int t = threadIdx.x;
    int start = blockIdx.x * TILE;

    for (int i = t; i < NPACK; i += THREADS) curP[i] = 0u;
    __syncthreads();

    // Phase A: read 12 pairs/thread (int4 x3, coalesced), keep in registers
    int cells[12];
    unsigned int lows[12];
#pragma unroll
    for (int j = 0; j < 3; ++j) {
        int base = start + j * (THREADS * 4) + t * 4;
        int k0 = j * 4;
        if (base + 3 < P) {
            int4 s = *reinterpret_cast<const int4*>(src_idx + base);
            int4 d = *reinterpret_cast<const int4*>(dst_idx + base);
            int4 l = *reinterpret_cast<const int4*>(path_len + base);
            int lp = base - start;
            cells[k0]     = s.x * n + d.x;
            cells[k0 + 1] = s.y * n + d.y;
            cells[k0 + 2] = s.z * n + d.z;
            cells[k0 + 3] = s.w * n + d.w;
            lows[k0]     = ((unsigned int)(lp + 1) << 3) | (unsigned int)((l.x < 5 ? l.x : 5) - 1);
            lows[k0 + 1] = ((unsigned int)(lp + 2) << 3) | (unsigned int)((l.y < 5 ? l.y : 5) - 1);
            lows[k0 + 2] = ((unsigned int)(lp + 3) << 3) | (unsigned int)((l.z < 5 ? l.z : 5) - 1);
            lows[k0 + 3] = ((unsigned int)(lp + 4) << 3) | (unsigned int)((l.w < 5 ? l.w : 5) - 1);
        } else {
#pragma unroll
            for (int jj = 0; jj < 4; ++jj) {
                int p = base + jj;
                if (p < P) {
                    cells[k0 + jj] = src_idx[p] * n + dst_idx[p];
                    int len = path_len[p];
                    int cl = (len < 5 ? len : 5) - 1;
                    lows[k0 + jj] = ((unsigned int)(p - start + 1) << 3) | (unsigned int)cl;
                } else {
                    cells[k0 + jj] = -1;
                    lows[k0 + jj] = 0u;
                }
            }
        }
    }
#pragma unroll
    for (int k = 0; k < 12; ++k) {
        if (cells[k] >= 0) {
            unsigned int c = (unsigned int)cells[k] >> BSHIFT;
            atomicAdd(&curP[c >> 1], (c & 1) ? 0x10000u : 1u);
        }
    }
    __syncthreads();

    // dump counts row for the scan kernel (curP holds counts right now)
    {
        unsigned int* crow = countsW + (size_t)blockIdx.x * NPACK;
        for (int i = t; i < NPACK; i += THREADS) crow[i] = curP[i];
    }

    // Phase B: block-wide exclusive scan of counts -> run starts (histP).
    // Buckets 2198/2199 count 0 => st[2198] == total (sentinel).
    unsigned int l0 = 0, l1 = 0, l2v = 0, l3 = 0, s = 0;
    if (t < NOWN) {
        unsigned int w0 = curP[2 * t], w1 = curP[2 * t + 1];
        unsigned int v0 = w0 & 0xFFFFu, v1 = w0 >> 16;
        unsigned int v2 = w1 & 0xFFFFu, v3 = w1 >> 16;
        l0 = 0; l1 = v0; l2v = v0 + v1; l3 = v0 + v1 + v2;
        s = v0 + v1 + v2 + v3;
    }
    unsigned int x = s;
    for (int d = 1; d < 64; d <<= 1) {
        unsigned int y = (unsigned int)__shfl_up((int)x, d, 64);
        if ((t & 63) >= d) x += y;
    }
    if ((t & 63) == 63) scr[t >> 6] = x;
    __syncthreads();
    if (t == 0) {
        unsigned int acc = 0;
        for (int w = 0; w < 16; ++w) { unsigned int v = scr[w]; scr[16 + w] = acc; acc += v; }
        scr[32] = acc;
    }
    __syncthreads();
    unsigned int exc = x - s + scr[16 + (t >> 6)];
    if (t < NOWN) {
        unsigned int st0 = exc + l0, st1 = exc + l1, st2 = exc + l2v, st3 = exc + l3;
        histP[2 * t]     = (st0 & 0xFFFFu) | (st1 << 16);
        histP[2 * t + 1] = (st2 & 0xFFFFu) | (st3 << 16);
    }
    __syncthreads();

    // Phase C: cursors := starts
    for (int i = t; i < NPACK; i += THREADS) curP[i] = histP[i];
    __syncthreads();

    // Phase D: place records into LDS staging, grouped by bucket
#pragma unroll
    for (int k = 0; k < 12; ++k) {
        if (cells[k] >= 0) {
            unsigned int cell = (unsigned int)cells[k];
            unsigned int c = cell >> BSHIFT;
            unsigned int old = atomicAdd(&curP[c >> 1], (c & 1) ? 0x10000u : 1u);
            unsigned int pos = (old >> ((c & 1) * 16)) & 0xFFFFu;
            stage[pos] = ((cell & (BCELLS - 1)) << 18) | lows[k];
        }
    }
    __syncthreads();

    // Phase E: contiguous vectorized dump of sorted records + starts row
    unsigned int tot = scr[32];
    uint4* dst4 = reinterpret_cast<uint4*>(recsW + (size_t)blockIdx.x * TILE);
    const uint4* st4 = reinterpret_cast<const uint4*>(stage);
    unsigned int n4 = (tot + 3) >> 2;
    for (unsigned int i = t; i < n4; i += THREADS) dst4[i] = st4[i];
    unsigned int* srow = startsW + (size_t)blockIdx.x * NPACK;
    for (int i = t; i < NPACK; i += THREADS) srow[i] = histP[i];
}

// ---------------- K2: per-bucket exclusive scan over blocks (R9 verbatim) ----------------
__global__ __launch_bounds__(256) void se_scan(
        unsigned int* __restrict__ countsW,   // in: counts, out: bases (in place)
        unsigned short* __restrict__ basesT,  // [NBUCK][nblk+1] u16, sentinel=total
        int nblk) {
    __shared__ unsigned short lds16[MAXBLK * SCAN_TB];   // 21 KB
    unsigned int* lds32 = reinterpret_cast<unsigned int*>(lds16);
    int t = threadIdx.x;
    int c0 = blockIdx.x * SCAN_TB;
    int w0 = c0 >> 1;
    int words = nblk * (SCAN_TB / 2);

    for (int i = t; i < words; i += 256) {
        int r = i >> 3, w = i & 7;
        if (w0 + w < NPACK)
            lds32[r * 8 + w] = countsW[(size_t)r * NPACK + w0 + w];
    }
    __syncthreads();

    if (t < SCAN_TB && c0 + t < NBUCK) {
        unsigned int acc = 0;
        for (int r = 0; r < nblk; ++r) {
            unsigned short v = lds16[r * SCAN_TB + t];
            lds16[r * SCAN_TB + t] = (unsigned short)acc;
            acc += v;
        }
        basesT[(size_t)(c0 + t) * (nblk + 1) + nblk] = (unsigned short)acc;  // sentinel
    }
    __syncthreads();

    for (int i = t; i < words; i += 256) {
        int r = i >> 3, w = i & 7;
        if (w0 + w < NPACK)
            countsW[(size_t)r * NPACK + w0 + w] = lds32[r * 8 + w];
    }
    for (int k = 0; k < SCAN_TB; ++k) {
        int c = c0 + k;
        if (c >= NBUCK) break;
        for (int r = t; r < nblk; r += 256)
            basesT[(size_t)c * (nblk + 1) + r] = lds16[r * SCAN_TB + k];
    }
}

// ---------------- K3: repack block-local recs -> bucket-contiguous (in d_out) ----------------
__global__ __launch_bounds__(THREADS) void se_repack(
        const unsigned int* __restrict__ recsW,
        const unsigned int* __restrict__ startsW,
        const unsigned int* __restrict__ gbasesW,   // countsW after scan
        unsigned int* __restrict__ outRecs) {       // d_out as u32
    __shared__ unsigned int histP[NPACK];
    __shared__ unsigned int gbaseP[NPACK];

    int t = threadIdx.x;
    int blk = blockIdx.x;
    const unsigned int* srow = startsW + (size_t)blk * NPACK;
    const unsigned int* grow = gbasesW + (size_t)blk * NPACK;
    for (int i = t; i < NPACK; i += THREADS) {
        histP[i] = srow[i];
        gbaseP[i] = grow[i];
    }
    __syncthreads();

    unsigned int tot = unpack16(histP, 2198);       // == total records this block
    const unsigned int* rr = recsW + (size_t)blk * TILE;
    for (unsigned int i = t; i < tot; i += THREADS) {
        unsigned int rec = rr[i];
        unsigned int lo = 0, hi = 2199;
        while (lo < hi) {
            unsigned int mid = (lo + hi + 1) >> 1;
            if (unpack16(histP, mid) <= i) lo = mid; else hi = mid - 1;
        }
        unsigned int c = lo;
        unsigned int pos = unpack16(gbaseP, c) + (i - unpack16(histP, c));
        outRecs[(size_t)c * BCELLS + pos] = rec;
    }
}

// ---------------- K4: per-bucket merge + decode (R9 verbatim) ----------------
__device__ __forceinline__ float se_decode(unsigned int k,
                                           float b0, float b1, float b2,
                                           float b3, float b4) {
    unsigned c = k & 7u;
    float t = (c == 0u) ? b0 : (c == 1u) ? b1 : (c == 2u) ? b2 : (c == 3u) ? b3 : b4;
    return k ? t : 0.0f;
}

__global__ __launch_bounds__(THREADS) void se_merge(
        const unsigned short* __restrict__ basesT,  // [NBUCK][nblk+1]
        const float* __restrict__ b,
        float* __restrict__ out,              // records live here too
        long long totalCells, int nblk) {
    __shared__ unsigned int tab[BCELLS];      // 64 KB

    int c = blockIdx.x;
    long long baseCell = (long long)c << BSHIFT;
    long long rem = totalCells - baseCell;
    int valid = rem < BCELLS ? (int)rem : BCELLS;

    uint4* tab4 = reinterpret_cast<uint4*>(tab);
    for (int i = threadIdx.x; i < BCELLS / 4; i += THREADS)
        tab4[i] = make_uint4(0u, 0u, 0u, 0u);
    __syncthreads();

    // one thread per block-run (runs are CONTIGUOUS in this bucket's region)
    const unsigned int* r =
        reinterpret_cast<const unsigned int*>(out) + (size_t)c * BCELLS;
    int tr = threadIdx.x;
    if (tr < nblk) {
        const unsigned short* B = basesT + (size_t)c * (nblk + 1);
        unsigned int rb0 = B[tr], rb1 = B[tr + 1];
        unsigned int keyhi = (unsigned int)(tr + 1) << 18;
        for (unsigned int i = rb0; i < rb1; ++i) {
            unsigned int rec = r[i];
            atomicMax(&tab[rec >> 18], keyhi | (rec & 0x3FFFFu));
        }
    }
    __syncthreads();

    float b0 = b[0], b1 = b[1], b2 = b[2], b3 = b[3], b4 = b[4];
    float* o = out + baseCell;
    int n4 = valid >> 2;
    float4* o4 = reinterpret_cast<float4*>(o);
    for (int i = threadIdx.x; i < n4; i += THREADS) {
        uint4 k = tab4[i];
        float4 v;
        v.x = se_decode(k.x, b0, b1, b2, b3, b4);
        v.y = se_decode(k.y, b0, b1, b2, b3, b4);
        v.z = se_decode(k.z, b0, b1, b2, b3, b4);
        v.w = se_decode(k.w, b0, b1, b2, b3, b4);
        o4[i] = v;
    }
    for (int i = (n4 << 2) + threadIdx.x; i < valid; i += THREADS)
        o[i] = se_decode(tab[i], b0, b1, b2, b3, b4);
}

extern "C" void kernel_launch(void* const* d_in, const int* in_sizes, int n_in,
                              void* d_out, int out_size, void* d_ws, size_t ws_size,
                              hipStream_t stream) {
    // inputs: 0=x [N*128 f32], 1=b [5 f32], 2=src_idx [P i32], 3=dst_idx [P i32], 4=path_len [P i32]
    const float* b        = (const float*)d_in[1];
    const int*   src_idx  = (const int*)d_in[2];
    const int*   dst_idx  = (const int*)d_in[3];
    const int*   path_len = (const int*)d_in[4];
    int P = in_sizes[2];
    int n = in_sizes[0] / 128;                      // N = 6000
    long long totalCells = (long long)n * n;        // 36,000,000
    int nblk = (P + TILE - 1) / TILE;               // 652

    // ws layout: recsW [nblk*TILE u32] (32MB), startsW [nblk*NPACK u32] (2.87MB),
    // countsW [nblk*NPACK u32] (2.87MB), basesT [NBUCK*(nblk+1) u16] (2.87MB).
    // All fully overwritten every call — no memset needed.
    unsigned int*   recsW   = (unsigned int*)d_ws;
    unsigned int*   startsW = recsW + (size_t)nblk * TILE;
    unsigned int*   countsW = startsW + (size_t)nblk * NPACK;
    unsigned short* basesT  = (unsigned short*)(countsW + (size_t)nblk * NPACK);

    // K1: per-tile LDS bucket-sort -> block-local sorted recs + counts + starts
    se_sort<<<nblk, THREADS, 0, stream>>>(src_idx, dst_idx, path_len,
                                          recsW, startsW, countsW, P, n);

    // K2: per-bucket exclusive scan over blocks -> bases (in countsW) + basesT
    se_scan<<<(NBUCK + SCAN_TB - 1) / SCAN_TB, 256, 0, stream>>>(countsW, basesT, nblk);

    // K3: repack to bucket-contiguous regions inside d_out
    se_repack<<<nblk, THREADS, 0, stream>>>(recsW, startsW, countsW,
                                            (unsigned int*)d_out);

    // K4: per-bucket contiguous gather-merge + decode + store
    se_merge<<<NBUCK, THREADS, 0, stream>>>(basesT, b, (float*)d_out,
                                            totalCells, nblk);
}